// Round 2
// baseline (391.304 us; speedup 1.0000x reference)
//
#include <hip/hip_runtime.h>

#define N_NODES   50000
#define HID       64
#define N_GRAPHS  128
#define N_CLASSES 10
#define NP        196           // partitions of 256 nodes (196*256 = 50176)
#define NPAD      50176         // NP*256

typedef __attribute__((ext_vector_type(8))) short short8;
typedef __attribute__((ext_vector_type(4))) float f32x4;

__device__ __forceinline__ unsigned bf16rne(float f) {
    unsigned u = __float_as_uint(f);
    return (u + 0x7fffu + ((u >> 16) & 1u)) >> 16;
}
__device__ __forceinline__ unsigned pack_bf16x2(float lo, float hi) {
    return bf16rne(lo) | (bf16rne(hi) << 16);
}

// Features are row-major bf16 [node][64] (r6-proven fastest layout).

// ---------------- x -> bf16 conversion + zero scratch (launched FIRST) ----
// Zero span: deg[NPAD] | sums[128*64] | cnt[128]  (contiguous ints)
#define NZERO (NPAD + N_GRAPHS * 64 + N_GRAPHS)

__global__ void cvt_kernel(const float* __restrict__ x, unsigned short* __restrict__ xb,
                           int* __restrict__ zspan) {
    int i = blockIdx.x * blockDim.x + threadIdx.x;
    if (i < NZERO) zspan[i] = 0;
    if (i < N_NODES * 16) {
        float4 v = ((const float4*)x)[i];
        uint2 o;
        o.x = pack_bf16x2(v.x, v.y);
        o.y = pack_bf16x2(v.z, v.w);
        ((uint2*)xb)[i] = o;
    }
}

// ---------------- CSR build: flat atomic histogram + scan + scatter -------
// deg histogram: 1.25M atomics over 50000 addresses (3125 lines, ~25/addr —
// low contention, unlike the old 196-counter/13-line hot spot).

__global__ __launch_bounds__(256) void count_kernel(
    const int* __restrict__ dst, int* __restrict__ deg, int E) {
    int e = blockIdx.x * 256 + threadIdx.x;
    if (e < E) atomicAdd(&deg[dst[e]], 1);
}

// 196 blocks; each block redundantly computes the 196 partition sums
// (wave-parallel, no barriers in the reduce), scans them in LDS, then does
// a local 256-scan of its own degrees and writes offsets + cursor.
__global__ __launch_bounds__(256) void offsets_kernel(
    const int* __restrict__ deg, int* __restrict__ offsets,
    int* __restrict__ cursor) {
    __shared__ int part[256];
    __shared__ int sc[256];
    const int p = blockIdx.x, t = threadIdx.x;
    const int w = t >> 6, lane = t & 63;

    // partition sums: wave w handles chunks c = w, w+4, ...
    for (int c = w; c < NP; c += 4) {
        int base = c * 256;
        int s = deg[base + lane] + deg[base + 64 + lane]
              + deg[base + 128 + lane] + deg[base + 192 + lane];
#pragma unroll
        for (int m = 1; m < 64; m <<= 1) s += __shfl_xor(s, m);
        if (lane == 0) part[c] = s;
    }
    if (t >= NP) part[t] = 0;
    __syncthreads();

    // inclusive scan of partition sums
    sc[t] = part[t];
    __syncthreads();
    for (int off = 1; off < 256; off <<= 1) {
        int add = (t >= off) ? sc[t - off] : 0;
        __syncthreads();
        sc[t] += add;
        __syncthreads();
    }
    const int pbase = sc[p] - part[p];      // exclusive prefix of partition p
    __syncthreads();

    // local scan of this block's 256 degrees
    const int node = p * 256 + t;
    const int d = (node < N_NODES) ? deg[node] : 0;
    sc[t] = d;
    __syncthreads();
    for (int off = 1; off < 256; off <<= 1) {
        int add = (t >= off) ? sc[t - off] : 0;
        __syncthreads();
        sc[t] += add;
        __syncthreads();
    }
    if (node <= N_NODES) {
        int o = pbase + sc[t] - d;          // exclusive
        offsets[node] = o;
        if (node < N_NODES) cursor[node] = o;   // scatter cursor = offsets
    }
}

__global__ __launch_bounds__(256) void scatter_kernel(
    const int* __restrict__ src, const int* __restrict__ dst,
    int* __restrict__ cursor, unsigned short* __restrict__ csr, int E) {
    int e = blockIdx.x * 256 + threadIdx.x;
    if (e < E) {
        int pos = atomicAdd(&cursor[dst[e]], 1);
        csr[pos] = (unsigned short)src[e];   // src < 50000 < 65536
    }
}

// ---------------- Gather: one wave per node, 32-edge rounds ----------------
// dwordx4 loads: 8 lanes cover one 128 B row, 8 rows per instruction.

__global__ __launch_bounds__(256) void gather_kernel(
    const unsigned short* __restrict__ hin,
    const int* __restrict__ offsets, const unsigned short* __restrict__ csr_src,
    unsigned short* __restrict__ agg) {
    const int w = threadIdx.x >> 6, lane = threadIdx.x & 63;
    const int rg = lane >> 3;          // row group: 8 rows per load instr
    const int cg = lane & 7;           // channel group: 8 ch (16 B) per lane
    const int n = blockIdx.x * 4 + w;  // grid = N/4 exactly
    const int beg = offsets[n], end = offsets[n + 1];

    float acc[8] = {0.f, 0.f, 0.f, 0.f, 0.f, 0.f, 0.f, 0.f};
    for (int base = beg; base < end; base += 64) {
        int cnt = min(64, end - base);
        int sidx = (base + lane < end) ? (int)csr_src[base + lane] : 0;
        for (int kb = 0; kb < cnt; kb += 32) {
            uint4 u[4];
#pragma unroll
            for (int p = 0; p < 4; ++p) {      // 4 independent 8-row loads
                int e = kb + 8 * p + rg;
                int r = __shfl(sidx, e);       // masked lanes see row 0 (safe)
                if (e < cnt)
                    u[p] = *((const uint4*)(hin + (size_t)r * 64) + cg);
                else
                    u[p] = make_uint4(0u, 0u, 0u, 0u);
            }
#pragma unroll
            for (int p = 0; p < 4; ++p) {
                acc[0] += __uint_as_float(u[p].x << 16);
                acc[1] += __uint_as_float(u[p].x & 0xffff0000u);
                acc[2] += __uint_as_float(u[p].y << 16);
                acc[3] += __uint_as_float(u[p].y & 0xffff0000u);
                acc[4] += __uint_as_float(u[p].z << 16);
                acc[5] += __uint_as_float(u[p].z & 0xffff0000u);
                acc[6] += __uint_as_float(u[p].w << 16);
                acc[7] += __uint_as_float(u[p].w & 0xffff0000u);
            }
        }
    }
    // combine the 8 row groups: sum over lane bits 3..5
#pragma unroll
    for (int m = 8; m <= 32; m <<= 1)
#pragma unroll
        for (int j = 0; j < 8; ++j)
            acc[j] += __shfl_xor(acc[j], m);
    if (rg == 0) {
        uint4 o;
        o.x = pack_bf16x2(acc[0], acc[1]);
        o.y = pack_bf16x2(acc[2], acc[3]);
        o.z = pack_bf16x2(acc[4], acc[5]);
        o.w = pack_bf16x2(acc[6], acc[7]);
        *((uint4*)(agg + (size_t)n * 64) + cg) = o;   // 8 lanes x 16 B = 128 B
    }
}

// ---------------- Linear: streaming MFMA (row-major, r6-proven) ----------

template <int RELU>
__global__ __launch_bounds__(256) void linear_kernel(
    const unsigned short* __restrict__ agg,
    const unsigned short* __restrict__ hin,
    const float* __restrict__ Wrel, const float* __restrict__ bias,
    const float* __restrict__ Wroot, unsigned short* __restrict__ hout) {
    __shared__ unsigned short outT[4][16][72];

    const int tid = threadIdx.x;
    const int w = tid >> 6, lane = tid & 63;
    const int q = lane >> 4, c = lane & 15;
    const int g0 = (blockIdx.x * 4 + w) * 16;
    if (g0 >= N_NODES) return;

    // weight B-fragments: B[k][o], o = t*16+c, k = s*32+q*8+j
    short8 brel[4][2], broot[4][2];
    float biasv[4];
#pragma unroll
    for (int t = 0; t < 4; ++t) {
        int o = t * 16 + c;
        biasv[t] = bias[o];
#pragma unroll
        for (int s = 0; s < 2; ++s) {
            const float4* pr = (const float4*)(Wrel  + o * 64 + s * 32 + q * 8);
            const float4* po = (const float4*)(Wroot + o * 64 + s * 32 + q * 8);
            float4 r0 = pr[0], r1 = pr[1], z0 = po[0], z1 = po[1];
            short8 rr, zz;
            rr[0] = (short)bf16rne(r0.x); rr[1] = (short)bf16rne(r0.y);
            rr[2] = (short)bf16rne(r0.z); rr[3] = (short)bf16rne(r0.w);
            rr[4] = (short)bf16rne(r1.x); rr[5] = (short)bf16rne(r1.y);
            rr[6] = (short)bf16rne(r1.z); rr[7] = (short)bf16rne(r1.w);
            zz[0] = (short)bf16rne(z0.x); zz[1] = (short)bf16rne(z0.y);
            zz[2] = (short)bf16rne(z0.z); zz[3] = (short)bf16rne(z0.w);
            zz[4] = (short)bf16rne(z1.x); zz[5] = (short)bf16rne(z1.y);
            zz[6] = (short)bf16rne(z1.z); zz[7] = (short)bf16rne(z1.w);
            brel[t][s] = rr; broot[t][s] = zz;
        }
    }

    // A fragments straight from global: A[m=c][k=s*32+q*8+j]
    const int na = min(g0 + c, N_NODES - 1);
    short8 a_agg[2], a_x[2];
#pragma unroll
    for (int s = 0; s < 2; ++s) {
        a_agg[s] = *(const short8*)(agg + (size_t)na * 64 + s * 32 + q * 8);
        a_x[s]   = *(const short8*)(hin + (size_t)na * 64 + s * 32 + q * 8);
    }

    f32x4 acc4[4];
#pragma unroll
    for (int t = 0; t < 4; ++t) {
        f32x4 a0 = {biasv[t], biasv[t], biasv[t], biasv[t]};
        a0 = __builtin_amdgcn_mfma_f32_16x16x32_bf16(a_agg[0], brel[t][0], a0, 0, 0, 0);
        a0 = __builtin_amdgcn_mfma_f32_16x16x32_bf16(a_agg[1], brel[t][1], a0, 0, 0, 0);
        a0 = __builtin_amdgcn_mfma_f32_16x16x32_bf16(a_x[0],  broot[t][0], a0, 0, 0, 0);
        a0 = __builtin_amdgcn_mfma_f32_16x16x32_bf16(a_x[1],  broot[t][1], a0, 0, 0, 0);
        acc4[t] = a0;
    }

    // ReLU + bf16 + per-wave LDS transpose (C/D: col=lane&15, row=q*4+reg)
#pragma unroll
    for (int t = 0; t < 4; ++t)
#pragma unroll
        for (int r = 0; r < 4; ++r) {
            float v = acc4[t][r];
            if (RELU) v = fmaxf(v, 0.f);
            outT[w][q * 4 + r][t * 16 + c] = (unsigned short)bf16rne(v);
        }
    // same-wave LDS RAW: compiler emits lgkmcnt wait; no barrier needed

#pragma unroll
    for (int it = 0; it < 2; ++it) {
        int row = it * 8 + (lane >> 3);
        int ch = (lane & 7) * 8;
        int n = g0 + row;
        if (n < N_NODES) {
            short8 v = *(const short8*)&outT[w][row][ch];
            *(short8*)(hout + (size_t)n * 64 + ch) = v;
        }
    }
}

// ---------------- Pooling: segmented (batch is sorted), row-major bf16 ---

__global__ __launch_bounds__(256) void pool_kernel(
    const unsigned short* __restrict__ h, const int* __restrict__ batch,
    float* __restrict__ sums, int* __restrict__ cnt) {
    int tid = threadIdx.x;
    int w = tid >> 6, lane = tid & 63;
    int n0 = blockIdx.x * 128 + w * 32;
    if (n0 >= N_NODES) return;
    int nend = min(n0 + 32, N_NODES);
    int cur = batch[n0];
    float acc = 0.f;
    int run = 0;
    for (int n = n0; n < nend; ++n) {
        int g = batch[n];                 // wave-uniform load
        if (g != cur) {
            atomicAdd(&sums[cur * 64 + lane], acc);
            if (lane == 0) atomicAdd(&cnt[cur], run);
            acc = 0.f; run = 0; cur = g;
        }
        unsigned u = h[(size_t)n * 64 + lane];
        acc += __uint_as_float(u << 16);
        run++;
    }
    atomicAdd(&sums[cur * 64 + lane], acc);
    if (lane == 0) atomicAdd(&cnt[cur], run);
}

__global__ void final_kernel(const float* __restrict__ sums, const int* __restrict__ cnt,
                             const float* __restrict__ Wlin, const float* __restrict__ blin,
                             float* __restrict__ out) {
    __shared__ float pl[64];
    int g = blockIdx.x, lane = threadIdx.x;
    float cdiv = fmaxf((float)cnt[g], 1.0f);
    float p = sums[g * 64 + lane] / cdiv;
    out[g * 64 + lane] = p;               // pooled output
    pl[lane] = p;
    __syncthreads();
    if (lane < N_CLASSES) {
        float o = blin[lane];
#pragma unroll
        for (int k = 0; k < 64; ++k) o += pl[k] * Wlin[lane * 64 + k];
        out[N_GRAPHS * 64 + g * N_CLASSES + lane] = o;  // classifier output
    }
}

// ---------------- Launch (12 dispatches, no memsets) ----------------

extern "C" void kernel_launch(void* const* d_in, const int* in_sizes, int n_in,
                              void* d_out, int out_size, void* d_ws, size_t ws_size,
                              hipStream_t stream) {
    const float* x     = (const float*)d_in[0];
    const int*   ei    = (const int*)d_in[1];
    const int*   batch = (const int*)d_in[2];
    const float* W1r = (const float*)d_in[3];
    const float* b1  = (const float*)d_in[4];
    const float* W1o = (const float*)d_in[5];
    const float* W2r = (const float*)d_in[6];
    const float* b2  = (const float*)d_in[7];
    const float* W2o = (const float*)d_in[8];
    const float* W3r = (const float*)d_in[9];
    const float* b3  = (const float*)d_in[10];
    const float* W3o = (const float*)d_in[11];
    const float* Wl  = (const float*)d_in[12];
    const float* bl  = (const float*)d_in[13];
    float* out = (float*)d_out;

    const int E = in_sizes[1] / 2;
    const int* src = ei;
    const int* dst = ei + E;

    char* p = (char*)d_ws;
    unsigned short* xb  = (unsigned short*)p; p += (size_t)N_NODES * 64 * 2;
    unsigned short* h1  = (unsigned short*)p; p += (size_t)N_NODES * 64 * 2;
    unsigned short* h2  = (unsigned short*)p; p += (size_t)N_NODES * 64 * 2;
    unsigned short* agg = (unsigned short*)p; p += (size_t)N_NODES * 64 * 2;
    unsigned short* h3  = h1;                  // layer-3 output reuses h1
    unsigned short* csr = (unsigned short*)p; p += ((size_t)E * 2 + 255) & ~255ull;
    int* offsets   = (int*)p;   p += (size_t)(N_NODES + 64) * 4;
    // ---- contiguous zero span (cvt zeroes NZERO ints from here) ----
    int* deg       = (int*)p;   p += (size_t)NPAD * 4;
    float* sums    = (float*)p; p += (size_t)N_GRAPHS * 64 * 4;
    int* cnt       = (int*)p;   p += N_GRAPHS * 4;
    // ---- end zero span ----
    int* cursor    = (int*)p;   p += (size_t)NPAD * 4;

    const int EB = (E + 255) / 256;        // 4883 blocks
    cvt_kernel<<<(N_NODES * 16 + 255) / 256, 256, 0, stream>>>(x, xb, deg);
    count_kernel<<<EB, 256, 0, stream>>>(dst, deg, E);
    offsets_kernel<<<NP, 256, 0, stream>>>(deg, offsets, cursor);
    scatter_kernel<<<EB, 256, 0, stream>>>(src, dst, cursor, csr, E);

    const int GB = N_NODES / 4;            // 12500 blocks, 1 wave per node
    const int LB = (N_NODES + 63) / 64;    // 782 blocks
    gather_kernel<<<GB, 256, 0, stream>>>(xb, offsets, csr, agg);
    linear_kernel<1><<<LB, 256, 0, stream>>>(agg, xb, W1r, b1, W1o, h1);
    gather_kernel<<<GB, 256, 0, stream>>>(h1, offsets, csr, agg);
    linear_kernel<1><<<LB, 256, 0, stream>>>(agg, h1, W2r, b2, W2o, h2);
    gather_kernel<<<GB, 256, 0, stream>>>(h2, offsets, csr, agg);
    linear_kernel<0><<<LB, 256, 0, stream>>>(agg, h2, W3r, b3, W3o, h3);

    pool_kernel<<<(N_NODES + 127) / 128, 256, 0, stream>>>(h3, batch, sums, cnt);
    final_kernel<<<N_GRAPHS, 64, 0, stream>>>(sums, cnt, Wl, bl, out);
}

// Round 3
// 263.016 us; speedup vs baseline: 1.4878x; 1.4878x over previous
//
#include <hip/hip_runtime.h>

#define N_NODES   50000
#define HID       64
#define N_GRAPHS  128
#define N_CLASSES 10
#define NP        196           // partitions of 256 nodes (196*256 = 50176)
#define EPA       8192          // edges per bucket block (r0-proven)
#define PCAP      8192          // per-partition capacity in packed[] (>20 sigma)

typedef __attribute__((ext_vector_type(8))) short short8;
typedef __attribute__((ext_vector_type(4))) float f32x4;

__device__ __forceinline__ unsigned bf16rne(float f) {
    unsigned u = __float_as_uint(f);
    return (u + 0x7fffu + ((u >> 16) & 1u)) >> 16;
}
__device__ __forceinline__ unsigned pack_bf16x2(float lo, float hi) {
    return bf16rne(lo) | (bf16rne(hi) << 16);
}

// Features are row-major bf16 [node][64] (r6-proven fastest layout).

// ---------------- x -> bf16 conversion + gcursor zero (launched FIRST) ----

__global__ void cvt_kernel(const float* __restrict__ x, unsigned short* __restrict__ xb,
                           int* __restrict__ gcursor) {
    if (blockIdx.x == 0 && threadIdx.x < NP) gcursor[threadIdx.x] = 0;
    int i = blockIdx.x * blockDim.x + threadIdx.x;
    if (i < N_NODES * 16) {
        float4 v = ((const float4*)x)[i];
        uint2 o;
        o.x = pack_bf16x2(v.x, v.y);
        o.y = pack_bf16x2(v.z, v.w);
        ((uint2*)xb)[i] = o;
    }
}

// ---------------- CSR build: 2-level LDS-staged counting sort -------------
// (r2 lesson: flat atomic scatter = 90us of random-RMW; keep the LDS sort.)

__global__ __launch_bounds__(256) void bucket_kernel(
    const int* __restrict__ src, const int* __restrict__ dst,
    int* __restrict__ gcursor, unsigned* __restrict__ packed, int E) {
    __shared__ int hist[NP], scp[NP], base[NP], cnt2[NP];
    __shared__ int sc[256];
    __shared__ unsigned stag[EPA];
    const int t = threadIdx.x;
    const int e0 = blockIdx.x * EPA;
    const int e1 = min(e0 + EPA, E);
    for (int i = t; i < NP; i += 256) { hist[i] = 0; cnt2[i] = 0; }
    __syncthreads();
    for (int e = e0 + t; e < e1; e += 256)
        atomicAdd(&hist[dst[e] >> 8], 1);
    __syncthreads();
    sc[t] = (t < NP) ? hist[t] : 0;
    __syncthreads();
    for (int off = 1; off < 256; off <<= 1) {
        int add = (t >= off) ? sc[t - off] : 0;
        __syncthreads();
        sc[t] += add;
        __syncthreads();
    }
    if (t < NP) {
        scp[t] = sc[t] - hist[t];
        if (hist[t] > 0) base[t] = atomicAdd(&gcursor[t], hist[t]);
    }
    __syncthreads();
    for (int e = e0 + t; e < e1; e += 256) {
        int d = dst[e], s = src[e];
        int p = d >> 8;
        int idx = scp[p] + atomicAdd(&cnt2[p], 1);
        stag[idx] = (unsigned)s | ((unsigned)(d & 255) << 16) | ((unsigned)p << 24);
    }
    __syncthreads();
    const int n = e1 - e0;
    for (int i = t; i < n; i += 256) {
        unsigned v = stag[i];
        int p = v >> 24;
        packed[(size_t)p * PCAP + base[p] + (i - scp[p])] = v & 0x00FFFFFFu;
    }
}

// One block per partition. Integrated pscan, node offsets, LDS csr scatter,
// coalesced copy out. Block 0 also zeroes sums for the fused pooling.
__global__ __launch_bounds__(256) void build_kernel(
    const unsigned* __restrict__ packed, const int* __restrict__ gcursor,
    int* __restrict__ offsets, unsigned short* __restrict__ csr,
    int* __restrict__ sums_zero) {
    __shared__ int hist[256], lofs[256], cnt[256], sc[256], gv[256];
    __shared__ unsigned short lcsr[PCAP];
    const int p = blockIdx.x, t = threadIdx.x;

    if (p == 0) {   // zero sums(128*64 f32) for linear3's fused pooling
        for (int i = t; i < N_GRAPHS * 64; i += 256) sums_zero[i] = 0;
    }

    int v = (t < NP) ? gcursor[t] : 0;
    sc[t] = v; gv[t] = v;
    __syncthreads();
    for (int off = 1; off < 256; off <<= 1) {
        int add = (t >= off) ? sc[t - off] : 0;
        __syncthreads();
        sc[t] += add;
        __syncthreads();
    }
    const int pb = sc[p] - gv[p];          // exclusive prefix at p
    const int ne = gv[p];
    if (p == NP - 1 && t == 0) offsets[N_NODES] = sc[NP - 1];
    __syncthreads();

    const unsigned* mypk = packed + (size_t)p * PCAP;
    hist[t] = 0; cnt[t] = 0;
    __syncthreads();
    for (int i = t; i < ne; i += 256)
        atomicAdd(&hist[(mypk[i] >> 16) & 255], 1);
    __syncthreads();
    sc[t] = hist[t];
    __syncthreads();
    for (int off = 1; off < 256; off <<= 1) {
        int add = (t >= off) ? sc[t - off] : 0;
        __syncthreads();
        sc[t] += add;
        __syncthreads();
    }
    lofs[t] = sc[t] - hist[t];
    int node = p * 256 + t;
    if (node < N_NODES) offsets[node] = pb + lofs[t];
    __syncthreads();
    for (int i = t; i < ne; i += 256) {
        unsigned vv = mypk[i];
        int dl = (vv >> 16) & 255;
        int slot = lofs[dl] + atomicAdd(&cnt[dl], 1);
        lcsr[slot] = (unsigned short)(vv & 0xFFFFu);
    }
    __syncthreads();
    for (int i = t; i < ne; i += 256) csr[pb + i] = lcsr[i];
}

// ---------------- Gather: one wave per node, 32-edge rounds ----------------
// dwordx4 loads: 8 lanes cover one 128 B row, 8 rows per instruction.

__global__ __launch_bounds__(256) void gather_kernel(
    const unsigned short* __restrict__ hin,
    const int* __restrict__ offsets, const unsigned short* __restrict__ csr_src,
    unsigned short* __restrict__ agg) {
    const int w = threadIdx.x >> 6, lane = threadIdx.x & 63;
    const int rg = lane >> 3;          // row group: 8 rows per load instr
    const int cg = lane & 7;           // channel group: 8 ch (16 B) per lane
    const int n = blockIdx.x * 4 + w;  // grid = N/4 exactly
    const int beg = offsets[n], end = offsets[n + 1];

    float acc[8] = {0.f, 0.f, 0.f, 0.f, 0.f, 0.f, 0.f, 0.f};
    for (int base = beg; base < end; base += 64) {
        int cnt = min(64, end - base);
        int sidx = (base + lane < end) ? (int)csr_src[base + lane] : 0;
        for (int kb = 0; kb < cnt; kb += 32) {
            uint4 u[4];
#pragma unroll
            for (int p = 0; p < 4; ++p) {      // 4 independent 8-row loads
                int e = kb + 8 * p + rg;
                int r = __shfl(sidx, e);       // masked lanes see row 0 (safe)
                if (e < cnt)
                    u[p] = *((const uint4*)(hin + (size_t)r * 64) + cg);
                else
                    u[p] = make_uint4(0u, 0u, 0u, 0u);
            }
#pragma unroll
            for (int p = 0; p < 4; ++p) {
                acc[0] += __uint_as_float(u[p].x << 16);
                acc[1] += __uint_as_float(u[p].x & 0xffff0000u);
                acc[2] += __uint_as_float(u[p].y << 16);
                acc[3] += __uint_as_float(u[p].y & 0xffff0000u);
                acc[4] += __uint_as_float(u[p].z << 16);
                acc[5] += __uint_as_float(u[p].z & 0xffff0000u);
                acc[6] += __uint_as_float(u[p].w << 16);
                acc[7] += __uint_as_float(u[p].w & 0xffff0000u);
            }
        }
    }
    // combine the 8 row groups: sum over lane bits 3..5
#pragma unroll
    for (int m = 8; m <= 32; m <<= 1)
#pragma unroll
        for (int j = 0; j < 8; ++j)
            acc[j] += __shfl_xor(acc[j], m);
    if (rg == 0) {
        uint4 o;
        o.x = pack_bf16x2(acc[0], acc[1]);
        o.y = pack_bf16x2(acc[2], acc[3]);
        o.z = pack_bf16x2(acc[4], acc[5]);
        o.w = pack_bf16x2(acc[6], acc[7]);
        *((uint4*)(agg + (size_t)n * 64) + cg) = o;   // 8 lanes x 16 B = 128 B
    }
}

// ---------------- Linear: streaming MFMA (row-major, r6-proven) ----------
// POOL=1 (layer 3): skip h3 entirely; pool D-fragments straight from regs.
// D layout: node = q*4 + r, channel = t*16 + c  (C/D col=lane&15 = B-col).

template <int RELU, int POOL>
__global__ __launch_bounds__(256) void linear_kernel(
    const unsigned short* __restrict__ agg,
    const unsigned short* __restrict__ hin,
    const float* __restrict__ Wrel, const float* __restrict__ bias,
    const float* __restrict__ Wroot, unsigned short* __restrict__ hout,
    const int* __restrict__ batch, float* __restrict__ sums) {
    const int tid = threadIdx.x;
    const int w = tid >> 6, lane = tid & 63;
    const int q = lane >> 4, c = lane & 15;
    const int g0 = (blockIdx.x * 4 + w) * 16;
    if (g0 >= N_NODES) return;

    // weight B-fragments: B[k][o], o = t*16+c, k = s*32+q*8+j
    short8 brel[4][2], broot[4][2];
    float biasv[4];
#pragma unroll
    for (int t = 0; t < 4; ++t) {
        int o = t * 16 + c;
        biasv[t] = bias[o];
#pragma unroll
        for (int s = 0; s < 2; ++s) {
            const float4* pr = (const float4*)(Wrel  + o * 64 + s * 32 + q * 8);
            const float4* po = (const float4*)(Wroot + o * 64 + s * 32 + q * 8);
            float4 r0 = pr[0], r1 = pr[1], z0 = po[0], z1 = po[1];
            short8 rr, zz;
            rr[0] = (short)bf16rne(r0.x); rr[1] = (short)bf16rne(r0.y);
            rr[2] = (short)bf16rne(r0.z); rr[3] = (short)bf16rne(r0.w);
            rr[4] = (short)bf16rne(r1.x); rr[5] = (short)bf16rne(r1.y);
            rr[6] = (short)bf16rne(r1.z); rr[7] = (short)bf16rne(r1.w);
            zz[0] = (short)bf16rne(z0.x); zz[1] = (short)bf16rne(z0.y);
            zz[2] = (short)bf16rne(z0.z); zz[3] = (short)bf16rne(z0.w);
            zz[4] = (short)bf16rne(z1.x); zz[5] = (short)bf16rne(z1.y);
            zz[6] = (short)bf16rne(z1.z); zz[7] = (short)bf16rne(z1.w);
            brel[t][s] = rr; broot[t][s] = zz;
        }
    }

    // A fragments straight from global: A[m=c][k=s*32+q*8+j]
    const int na = min(g0 + c, N_NODES - 1);
    short8 a_agg[2], a_x[2];
#pragma unroll
    for (int s = 0; s < 2; ++s) {
        a_agg[s] = *(const short8*)(agg + (size_t)na * 64 + s * 32 + q * 8);
        a_x[s]   = *(const short8*)(hin + (size_t)na * 64 + s * 32 + q * 8);
    }

    f32x4 acc4[4];
#pragma unroll
    for (int t = 0; t < 4; ++t) {
        f32x4 a0 = {biasv[t], biasv[t], biasv[t], biasv[t]};
        a0 = __builtin_amdgcn_mfma_f32_16x16x32_bf16(a_agg[0], brel[t][0], a0, 0, 0, 0);
        a0 = __builtin_amdgcn_mfma_f32_16x16x32_bf16(a_agg[1], brel[t][1], a0, 0, 0, 0);
        a0 = __builtin_amdgcn_mfma_f32_16x16x32_bf16(a_x[0],  broot[t][0], a0, 0, 0, 0);
        a0 = __builtin_amdgcn_mfma_f32_16x16x32_bf16(a_x[1],  broot[t][1], a0, 0, 0, 0);
        acc4[t] = a0;
    }

    if (POOL) {
        // batch sorted: wave's 16 nodes almost always one graph
        int b0 = batch[g0], b15 = batch[g0 + 15];
        if (b0 == b15) {
#pragma unroll
            for (int t = 0; t < 4; ++t) {
                float s = acc4[t][0] + acc4[t][1] + acc4[t][2] + acc4[t][3];
                s += __shfl_xor(s, 16);          // sum over q (lane bits 4-5)
                s += __shfl_xor(s, 32);
                if (q == 0) atomicAdd(&sums[b0 * 64 + t * 16 + c], s);
            }
        } else {                                  // graph boundary (~4% waves)
#pragma unroll
            for (int r = 0; r < 4; ++r) {
                int bq = batch[g0 + q * 4 + r];
#pragma unroll
                for (int t = 0; t < 4; ++t)
                    atomicAdd(&sums[bq * 64 + t * 16 + c], acc4[t][r]);
            }
        }
    } else {
        // ReLU + bf16 + per-wave LDS transpose (node=q*4+r, ch=t*16+c)
        __shared__ unsigned short outT[4][16][72];
#pragma unroll
        for (int t = 0; t < 4; ++t)
#pragma unroll
            for (int r = 0; r < 4; ++r) {
                float v = acc4[t][r];
                if (RELU) v = fmaxf(v, 0.f);
                outT[w][q * 4 + r][t * 16 + c] = (unsigned short)bf16rne(v);
            }
        // same-wave LDS RAW: compiler emits lgkmcnt wait; no barrier needed
#pragma unroll
        for (int it = 0; it < 2; ++it) {
            int row = it * 8 + (lane >> 3);
            int ch = (lane & 7) * 8;
            int n = g0 + row;
            if (n < N_NODES) {
                short8 v = *(const short8*)&outT[w][row][ch];
                *(short8*)(hout + (size_t)n * 64 + ch) = v;
            }
        }
    }
}

// ---------------- Final: counts via binary search on sorted batch ---------

__global__ void final_kernel(const float* __restrict__ sums, const int* __restrict__ batch,
                             const float* __restrict__ Wlin, const float* __restrict__ blin,
                             float* __restrict__ out) {
    __shared__ float pl[64];
    int g = blockIdx.x, lane = threadIdx.x;
    // lower_bound(g) and lower_bound(g+1) — uniform across lanes, L2-cached
    int lo = 0, hi = N_NODES;
    while (lo < hi) { int m = (lo + hi) >> 1; if (batch[m] < g) lo = m + 1; else hi = m; }
    int s0 = lo;
    lo = 0; hi = N_NODES;
    while (lo < hi) { int m = (lo + hi) >> 1; if (batch[m] < g + 1) lo = m + 1; else hi = m; }
    float cdiv = fmaxf((float)(lo - s0), 1.0f);
    float p = sums[g * 64 + lane] / cdiv;
    out[g * 64 + lane] = p;               // pooled output
    pl[lane] = p;
    __syncthreads();
    if (lane < N_CLASSES) {
        float o = blin[lane];
#pragma unroll
        for (int k = 0; k < 64; ++k) o += pl[k] * Wlin[lane * 64 + k];
        out[N_GRAPHS * 64 + g * N_CLASSES + lane] = o;  // classifier output
    }
}

// ---------------- Launch (10 dispatches, no memsets) ----------------

extern "C" void kernel_launch(void* const* d_in, const int* in_sizes, int n_in,
                              void* d_out, int out_size, void* d_ws, size_t ws_size,
                              hipStream_t stream) {
    const float* x     = (const float*)d_in[0];
    const int*   ei    = (const int*)d_in[1];
    const int*   batch = (const int*)d_in[2];
    const float* W1r = (const float*)d_in[3];
    const float* b1  = (const float*)d_in[4];
    const float* W1o = (const float*)d_in[5];
    const float* W2r = (const float*)d_in[6];
    const float* b2  = (const float*)d_in[7];
    const float* W2o = (const float*)d_in[8];
    const float* W3r = (const float*)d_in[9];
    const float* b3  = (const float*)d_in[10];
    const float* W3o = (const float*)d_in[11];
    const float* Wl  = (const float*)d_in[12];
    const float* bl  = (const float*)d_in[13];
    float* out = (float*)d_out;

    const int E = in_sizes[1] / 2;
    const int* src = ei;
    const int* dst = ei + E;

    char* p = (char*)d_ws;
    unsigned short* xb  = (unsigned short*)p; p += (size_t)N_NODES * 64 * 2;
    unsigned short* h1  = (unsigned short*)p; p += (size_t)N_NODES * 64 * 2;
    unsigned short* h2  = (unsigned short*)p; p += (size_t)N_NODES * 64 * 2;
    unsigned short* agg = (unsigned short*)p; p += (size_t)N_NODES * 64 * 2;
    unsigned* packed    = (unsigned*)p; p += (size_t)NP * PCAP * 4;
    unsigned short* csr = (unsigned short*)p; p += (size_t)E * 2;
    int* offsets   = (int*)p;   p += (size_t)(N_NODES + 1) * 4;
    int* gcursor   = (int*)p;   p += NP * 4;
    float* sums    = (float*)p; p += (size_t)N_GRAPHS * 64 * 4;

    const int NCHUNK = (E + EPA - 1) / EPA;  // 153
    cvt_kernel<<<(N_NODES * 16 + 255) / 256, 256, 0, stream>>>(x, xb, gcursor);
    bucket_kernel<<<NCHUNK, 256, 0, stream>>>(src, dst, gcursor, packed, E);
    build_kernel<<<NP, 256, 0, stream>>>(packed, gcursor, offsets, csr, (int*)sums);

    const int GB = N_NODES / 4;            // 12500 blocks, 1 wave per node
    const int LB = (N_NODES + 63) / 64;    // 782 blocks
    gather_kernel<<<GB, 256, 0, stream>>>(xb, offsets, csr, agg);
    linear_kernel<1, 0><<<LB, 256, 0, stream>>>(agg, xb, W1r, b1, W1o, h1, batch, sums);
    gather_kernel<<<GB, 256, 0, stream>>>(h1, offsets, csr, agg);
    linear_kernel<1, 0><<<LB, 256, 0, stream>>>(agg, h1, W2r, b2, W2o, h2, batch, sums);
    gather_kernel<<<GB, 256, 0, stream>>>(h2, offsets, csr, agg);
    linear_kernel<0, 1><<<LB, 256, 0, stream>>>(agg, h2, W3r, b3, W3o, h1, batch, sums);

    final_kernel<<<N_GRAPHS, 64, 0, stream>>>(sums, batch, Wl, bl, out);
}